// Round 5
// baseline (1283.618 us; speedup 1.0000x reference)
//
#include <hip/hip_runtime.h>
#include <hip/hip_bf16.h>
#include <cstdint>
#include <cstddef>

// Problem constants (from reference)
#define NPTS  1000000
#define BSEG  2000
#define DIN   16
#define HDIM  256
#define DOUT  128
#define NTILE (NPTS / 32)   // 31250 tiles of 32 points
#define NWG   512           // 2 WGs/CU x 256 CUs

typedef __bf16          bf16x8 __attribute__((ext_vector_type(8)));
typedef unsigned short  us16x8 __attribute__((ext_vector_type(8)));
typedef unsigned int    u32x4  __attribute__((ext_vector_type(4)));
typedef float           f32x4  __attribute__((ext_vector_type(4)));

static __device__ __forceinline__ unsigned short f2bf(float x) {
    unsigned int u = __float_as_uint(x);
    u += 0x7fffu + ((u >> 16) & 1u);
    return (unsigned short)(u >> 16);
}

static __device__ __forceinline__ bf16x8 ldb8(const unsigned short* p) {
    u32x4 v = *(const u32x4*)p;
    return __builtin_bit_cast(bf16x8, v);
}
static __device__ __forceinline__ f32x4 mfma16(bf16x8 a, bf16x8 b, f32x4 c) {
    return __builtin_amdgcn_mfma_f32_16x16x32_bf16(a, b, c, 0, 0, 0);
}
static __device__ __forceinline__ void keep(bf16x8& v) {
    u32x4 u = __builtin_bit_cast(u32x4, v);
    unsigned a0 = u[0], a1 = u[1], a2 = u[2], a3 = u[3];
    asm volatile("" : "+v"(a0), "+v"(a1), "+v"(a2), "+v"(a3));
    u32x4 r; r[0] = a0; r[1] = a1; r[2] = a2; r[3] = a3;
    v = __builtin_bit_cast(bf16x8, r);
}

// async 16B/lane global->LDS: dest = lds base + lane*16 (wave-uniform base)
static __device__ __forceinline__ void async16(const float* g, float* l) {
    __builtin_amdgcn_global_load_lds(
        (const __attribute__((address_space(1))) void*)g,
        (__attribute__((address_space(3))) void*)l, 16, 0, 0);
}

// Sum across the 16 lanes of a DPP row via row_ror 8/4/2/1 (VALU-pipe).
static __device__ __forceinline__ float rsum16(float x) {
    x += __builtin_bit_cast(float, __builtin_amdgcn_update_dpp(
             0, __builtin_bit_cast(int, x), 0x128, 0xf, 0xf, false)); // ror:8
    x += __builtin_bit_cast(float, __builtin_amdgcn_update_dpp(
             0, __builtin_bit_cast(int, x), 0x124, 0xf, 0xf, false)); // ror:4
    x += __builtin_bit_cast(float, __builtin_amdgcn_update_dpp(
             0, __builtin_bit_cast(int, x), 0x122, 0xf, 0xf, false)); // ror:2
    x += __builtin_bit_cast(float, __builtin_amdgcn_update_dpp(
             0, __builtin_bit_cast(int, x), 0x121, 0xf, 0xf, false)); // ror:1
    return x;
}

// ---------------------------------------------------------------------------
__global__ __launch_bounds__(1024) void scan_counts(const int* __restrict__ counts,
                                                    int* __restrict__ offsets) {
    __shared__ int a[2048];
    const int t = threadIdx.x;
    a[t]        = (t        < BSEG) ? counts[t]        : 0;
    a[t + 1024] = (t + 1024 < BSEG) ? counts[t + 1024] : 0;
    for (int s = 1; s < 2048; s <<= 1) {
        __syncthreads();
        int x1 = (t >= s) ? a[t - s] : 0;
        int x2 = a[t + 1024 - s];
        __syncthreads();
        a[t] += x1;
        a[t + 1024] += x2;
    }
    __syncthreads();
    if (t == 0) offsets[0] = 0;
    offsets[t + 1] = a[t];
    if (t + 1024 < BSEG) offsets[t + 1025] = a[t + 1024];
}

__global__ __launch_bounds__(256) void fill_seg(const int* __restrict__ offsets,
                                                unsigned short* __restrict__ seg) {
    const int b  = blockIdx.x;
    const int lo = offsets[b], hi = offsets[b + 1];
    for (int i = lo + threadIdx.x; i < hi; i += 256) seg[i] = (unsigned short)b;
}

// W1T [256][32] (K zero-padded 16->32), W2T [256][256]; [n][k]-major bf16.
__global__ __launch_bounds__(256) void prep_weights(const float* __restrict__ W1,
                                                    const float* __restrict__ W2,
                                                    unsigned short* __restrict__ w1t,
                                                    unsigned short* __restrict__ w2t) {
    const int i = blockIdx.x * 256 + threadIdx.x;
    if (i < HDIM * 32) {
        int n = i >> 5, k = i & 31;
        w1t[i] = (k < DIN) ? f2bf(W1[k * HDIM + n]) : (unsigned short)0;
    } else {
        int j = i - HDIM * 32;
        if (j < HDIM * HDIM) {
            int n = j >> 8, k = j & 255;
            w2t[j] = f2bf(W2[k * HDIM + n]);
        }
    }
}

// ---------------------------------------------------------------------------
// Persistent fused kernel, 512 threads / 8 waves, tile M=32.
// Wave w owns cols [w*32, w*32+32): W2 slab = 64 VGPRs/wave, target 4
// waves/SIMD (2 WGs/CU).  z staged via async global_load_lds
// (double-buffered).  LN stats via DPP row-sums + cross-wave LDS combine.
// h1 row stride 264 ushort = 528 B (16B multiple — ds_read_b128 alignment
// REQUIRES this; 268 broke odd rows, R4 failure).  seg_sm loaded for the
// CURRENT tile at loop top (prefetching it raced with end-of-iter readers,
// R4 failure #2).
// MFMA layouts: A[m=lane&15][k=quad*8+j]; B[k=quad*8+j][n=lane&15];
// D[row=quad*4+reg][col=lane&15].
// ---------------------------------------------------------------------------
__global__ __launch_bounds__(512, 4) void fused_phi_pool(
    const float* __restrict__ z,
    const unsigned short* __restrict__ w1t,
    const unsigned short* __restrict__ w2t,
    const float* __restrict__ b1, const float* __restrict__ g1, const float* __restrict__ be1,
    const float* __restrict__ b2, const float* __restrict__ g2, const float* __restrict__ be2,
    const unsigned short* __restrict__ seg,
    float* __restrict__ sums_h) {
    __shared__ __align__(16) unsigned short h1[32][264];   // 16.5 KB
    __shared__ __align__(16) float part[2][32][16];        // 4 KB
    __shared__ __align__(16) float z_lds[2][32][16];       // 4 KB
    __shared__ __align__(16) int   seg_sm[2][32];

    const int tid  = threadIdx.x;
    const int wave = tid >> 6;
    const int lane = tid & 63;
    const int l15  = lane & 15;
    const int quad = lane >> 4;
    const bool zl  = (quad < 2);      // lanes carrying layer-1 A data (k<16)

    // ---- one-time: register-resident weight fragments (2 n-tiles/wave) ----
    bf16x8 bw1[2];
    bf16x8 bw2[2][8];
#pragma unroll
    for (int t = 0; t < 2; ++t) {
        const int n = wave * 32 + t * 16 + l15;
        bw1[t] = ldb8(w1t + n * 32 + quad * 8);
        keep(bw1[t]);
#pragma unroll
        for (int ks = 0; ks < 8; ++ks) {
            bw2[t][ks] = ldb8(w2t + n * 256 + ks * 32 + quad * 8);
            keep(bw2[t][ks]);
        }
    }
    float b1v[2], g1v[2], e1v[2], b2v[2], g2v[2], e2v[2];
#pragma unroll
    for (int t = 0; t < 2; ++t) {
        const int c = wave * 32 + t * 16 + l15;
        b1v[t] = b1[c]; g1v[t] = g1[c]; e1v[t] = be1[c];
        b2v[t] = b2[c]; g2v[t] = g2[c]; e2v[t] = be2[c];
    }

    // ---- prologue: stage z for first tile into buffer 0 ----
    if (wave == 0) {
        const float* gp = z + (size_t)blockIdx.x * 512 + lane * 4;
        async16(gp,       &z_lds[0][0][0]);
        async16(gp + 256, &z_lds[0][16][0]);
    }
    asm volatile("s_waitcnt vmcnt(0)");
    __syncthreads();

    int p = 0;
    for (int tile = blockIdx.x; tile < NTILE; tile += NWG, p ^= 1) {
        // seg ids for the CURRENT tile (read at end of this iteration; the
        // p-parity buffer keeps it clear of next iteration's write to p^1)
        if (tid < 32) seg_sm[p][tid] = (int)seg[tile * 32 + tid];

        // prefetch next tile's z into buffer p^1 (drained by B1's vmcnt(0))
        const int ntile = tile + NWG;
        if (wave == 0 && ntile < NTILE) {
            const float* gp = z + (size_t)ntile * 512 + lane * 4;
            async16(gp,       &z_lds[p ^ 1][0][0]);
            async16(gp + 256, &z_lds[p ^ 1][16][0]);
        }

        // ---------------- layer 1 (K=16 zero-padded to 32) ----------------
        f32x4 a1[2][2];
#pragma unroll
        for (int mb = 0; mb < 2; ++mb) {
            bf16x8 af;
            if (zl) {
                f32x4 v0 = *(const f32x4*)&z_lds[p][mb * 16 + l15][quad * 8];
                f32x4 v1 = *(const f32x4*)&z_lds[p][mb * 16 + l15][quad * 8 + 4];
                us16x8 u;
                u[0] = f2bf(v0[0]); u[1] = f2bf(v0[1]); u[2] = f2bf(v0[2]); u[3] = f2bf(v0[3]);
                u[4] = f2bf(v1[0]); u[5] = f2bf(v1[1]); u[6] = f2bf(v1[2]); u[7] = f2bf(v1[3]);
                af = __builtin_bit_cast(bf16x8, u);
            } else {
                us16x8 u = {0, 0, 0, 0, 0, 0, 0, 0};
                af = __builtin_bit_cast(bf16x8, u);
            }
            const f32x4 zero = {0.f, 0.f, 0.f, 0.f};
#pragma unroll
            for (int t = 0; t < 2; ++t) a1[mb][t] = mfma16(af, bw1[t], zero);
        }
        // bias + LN stats partials (per-row sum/sumsq over this wave's 32 cols)
#pragma unroll
        for (int mb = 0; mb < 2; ++mb) {
#pragma unroll
            for (int r = 0; r < 4; ++r) {
                float y0 = a1[mb][0][r] + b1v[0];
                float y1 = a1[mb][1][r] + b1v[1];
                a1[mb][0][r] = y0; a1[mb][1][r] = y1;
                float sv = rsum16(y0 + y1);
                float qv = rsum16(y0 * y0 + y1 * y1);
                if (l15 == 0)
                    *(float2*)&part[p][mb * 16 + quad * 4 + r][wave * 2] =
                        make_float2(sv, qv);
            }
        }
        __syncthreads();   // B1: stats visible; z prefetch drained; h1 free
        // normalize + relu -> bf16 h1
#pragma unroll
        for (int mb = 0; mb < 2; ++mb) {
#pragma unroll
            for (int r = 0; r < 4; ++r) {
                const int row = mb * 16 + quad * 4 + r;
                const float* pr = &part[p][row][0];
                float4 pa = *(const float4*)(pr);
                float4 pb = *(const float4*)(pr + 4);
                float4 pc = *(const float4*)(pr + 8);
                float4 pd = *(const float4*)(pr + 12);
                float st = (pa.x + pa.z) + (pb.x + pb.z) + (pc.x + pc.z) + (pd.x + pd.z);
                float qt = (pa.y + pa.w) + (pb.y + pb.w) + (pc.y + pc.w) + (pd.y + pd.w);
                float mean = st * (1.f / 256.f);
                float var  = qt * (1.f / 256.f) - mean * mean;
                float rs   = rsqrtf(fmaxf(var, 0.f) + 1e-5f);
#pragma unroll
                for (int t = 0; t < 2; ++t) {
                    float A = rs * g1v[t];
                    float y = fmaxf(fmaf(a1[mb][t][r], A, fmaf(-mean, A, e1v[t])), 0.f);
                    h1[row][wave * 32 + t * 16 + l15] = f2bf(y);
                }
            }
        }
        __syncthreads();   // B2: h1 ready

        // ---------------- layer 2 ----------------
        f32x4 a2[2][2];
#pragma unroll
        for (int mb = 0; mb < 2; ++mb) {
            const f32x4 zero = {0.f, 0.f, 0.f, 0.f};
            a2[mb][0] = zero; a2[mb][1] = zero;
#pragma unroll
            for (int ks = 0; ks < 8; ++ks) {
                bf16x8 af = ldb8(&h1[mb * 16 + l15][ks * 32 + quad * 8]);
#pragma unroll
                for (int t = 0; t < 2; ++t) a2[mb][t] = mfma16(af, bw2[t][ks], a2[mb][t]);
            }
        }
        // bias + LN stats partials
#pragma unroll
        for (int mb = 0; mb < 2; ++mb) {
#pragma unroll
            for (int r = 0; r < 4; ++r) {
                float y0 = a2[mb][0][r] + b2v[0];
                float y1 = a2[mb][1][r] + b2v[1];
                a2[mb][0][r] = y0; a2[mb][1][r] = y1;
                float sv = rsum16(y0 + y1);
                float qv = rsum16(y0 * y0 + y1 * y1);
                if (l15 == 0)
                    *(float2*)&part[p][mb * 16 + quad * 4 + r][wave * 2] =
                        make_float2(sv, qv);
            }
        }
        __syncthreads();   // B3: layer-2 stats visible
        // normalize + relu in registers (h2 never hits LDS)
#pragma unroll
        for (int mb = 0; mb < 2; ++mb) {
#pragma unroll
            for (int r = 0; r < 4; ++r) {
                const int row = mb * 16 + quad * 4 + r;
                const float* pr = &part[p][row][0];
                float4 pa = *(const float4*)(pr);
                float4 pb = *(const float4*)(pr + 4);
                float4 pc = *(const float4*)(pr + 8);
                float4 pd = *(const float4*)(pr + 12);
                float st = (pa.x + pa.z) + (pb.x + pb.z) + (pc.x + pc.z) + (pd.x + pd.z);
                float qt = (pa.y + pa.w) + (pb.y + pb.w) + (pc.y + pc.w) + (pd.y + pd.w);
                float mean = st * (1.f / 256.f);
                float var  = qt * (1.f / 256.f) - mean * mean;
                float rs   = rsqrtf(fmaxf(var, 0.f) + 1e-5f);
#pragma unroll
                for (int t = 0; t < 2; ++t) {
                    float A = rs * g2v[t];
                    a2[mb][t][r] =
                        fmaxf(fmaf(a2[mb][t][r], A, fmaf(-mean, A, e2v[t])), 0.f);
                }
            }
        }

        // ---------------- ragged segment-sum of h2 (fp32) ----------------
        const int s0  = seg_sm[p][0];
        const int s31 = seg_sm[p][31];
        if (s0 == s31) {   // tile entirely inside one segment (~94%)
#pragma unroll
            for (int t = 0; t < 2; ++t) {
                float cs = a2[0][t][0] + a2[0][t][1] + a2[0][t][2] + a2[0][t][3]
                         + a2[1][t][0] + a2[1][t][1] + a2[1][t][2] + a2[1][t][3];
                cs += __shfl_xor(cs, 16, 64);
                cs += __shfl_xor(cs, 32, 64);
                if (quad == 0)
                    atomicAdd(&sums_h[s0 * HDIM + wave * 32 + t * 16 + l15], cs);
            }
        } else {           // exactly 2 segments (min count 100 > 32)
            const int* sgp = &seg_sm[p][0];
            float m0[4], m1[4];
#pragma unroll
            for (int r = 0; r < 4; ++r) {
                m0[r] = (sgp[quad * 4 + r]      == s0) ? 1.f : 0.f;
                m1[r] = (sgp[16 + quad * 4 + r] == s0) ? 1.f : 0.f;
            }
#pragma unroll
            for (int t = 0; t < 2; ++t) {
                float cs = 0.f, ca = 0.f;
#pragma unroll
                for (int r = 0; r < 4; ++r) {
                    cs += a2[0][t][r] + a2[1][t][r];
                    ca = fmaf(a2[0][t][r], m0[r], ca);
                    ca = fmaf(a2[1][t][r], m1[r], ca);
                }
                cs += __shfl_xor(cs, 16, 64);
                cs += __shfl_xor(cs, 32, 64);
                ca += __shfl_xor(ca, 16, 64);
                ca += __shfl_xor(ca, 32, 64);
                if (quad == 0) {
                    const int c = wave * 32 + t * 16 + l15;
                    atomicAdd(&sums_h[s0  * HDIM + c], ca);
                    atomicAdd(&sums_h[s31 * HDIM + c], cs - ca);
                }
            }
        }
    }
}

// ---------------------------------------------------------------------------
// emb[b] = (sums_h[b] @ W3) / count_b + b3
// ---------------------------------------------------------------------------
__global__ __launch_bounds__(256) void emb_gemm(const float* __restrict__ sums_h,
                                                const float* __restrict__ W3,
                                                const float* __restrict__ b3,
                                                const int* __restrict__ counts,
                                                float* __restrict__ emb) {
    const int b = blockIdx.x * 2 + (threadIdx.x >> 7);
    const int o = threadIdx.x & 127;
    const float* sh = sums_h + b * HDIM;
    float acc = 0.f;
#pragma unroll 8
    for (int k = 0; k < HDIM; ++k) acc = fmaf(sh[k], W3[k * DOUT + o], acc);
    emb[b * DOUT + o] = acc / (float)counts[b] + b3[o];
}

// ---------------------------------------------------------------------------
// out[n] = emb[seg[n]] ; 32 B/thread, nontemporal (out never re-read)
// ---------------------------------------------------------------------------
__global__ __launch_bounds__(256) void broadcast_out(const float* __restrict__ emb,
                                                     const unsigned short* __restrict__ seg,
                                                     float* __restrict__ out) {
    const int idx = blockIdx.x * 256 + threadIdx.x;   // n*16 + oct, exactly N*16
    const int n = idx >> 4, oct = idx & 15;
    const int s = seg[n];
    const f32x4* ev = (const f32x4*)emb;
    f32x4 v0 = ev[s * 32 + oct * 2];
    f32x4 v1 = ev[s * 32 + oct * 2 + 1];
    __builtin_nontemporal_store(v0, (f32x4*)out + idx * 2);
    __builtin_nontemporal_store(v1, (f32x4*)out + idx * 2 + 1);
}

// ---------------------------------------------------------------------------
extern "C" void kernel_launch(void* const* d_in, const int* in_sizes, int n_in,
                              void* d_out, int out_size, void* d_ws, size_t ws_size,
                              hipStream_t stream) {
    const float* z   = (const float*)d_in[0];
    const float* W1  = (const float*)d_in[1];
    const float* b1  = (const float*)d_in[2];
    const float* g1  = (const float*)d_in[3];
    const float* be1 = (const float*)d_in[4];
    const float* W2  = (const float*)d_in[5];
    const float* b2  = (const float*)d_in[6];
    const float* g2  = (const float*)d_in[7];
    const float* be2 = (const float*)d_in[8];
    const float* W3  = (const float*)d_in[9];
    const float* b3  = (const float*)d_in[10];
    const int* counts = (const int*)d_in[11];
    float* out = (float*)d_out;

    char* ws = (char*)d_ws;
    float*          sums_h  = (float*)(ws);                     // 2,048,000 B
    float*          emb     = (float*)(ws + 2048000);           // 1,024,000 B
    int*            offsets = (int*)  (ws + 3072000);           //     8,016 B
    unsigned short* seg     = (unsigned short*)(ws + 3080016);  // 2,000,000 B
    unsigned short* w1t     = (unsigned short*)(ws + 5080016);  //    16,384 B
    unsigned short* w2t     = (unsigned short*)(ws + 5096400);  //   131,072 B

    hipMemsetAsync(sums_h, 0, (size_t)BSEG * HDIM * sizeof(float), stream);
    scan_counts<<<1, 1024, 0, stream>>>(counts, offsets);
    fill_seg<<<BSEG, 256, 0, stream>>>(offsets, seg);
    prep_weights<<<(HDIM * 32 + HDIM * HDIM) / 256, 256, 0, stream>>>(W1, W2, w1t, w2t);
    fused_phi_pool<<<NWG, 512, 0, stream>>>(z, w1t, w2t,
                                            b1, g1, be1, b2, g2, be2,
                                            seg, sums_h);
    emb_gemm<<<BSEG / 2, 256, 0, stream>>>(sums_h, W3, b3, counts, emb);
    broadcast_out<<<NPTS * 16 / 256, 256, 0, stream>>>(emb, seg, out);
}